// Round 15
// baseline (216.394 us; speedup 1.0000x reference)
//
#include <hip/hip_runtime.h>
#include <hip/hip_bf16.h>
#include <type_traits>

// ---------------------------------------------------------------------------
// Problem constants
//   x: (8,128,128,256) f32   z: (8,64,64,256) f32   mask: (1,8,8,8,256,64) int
//   Wq (256,256) bq(256)  Wkv (256,512) bkv(512)  Wo (256,256) bo(256)
//   rel_table (900,8) f32   out: (8,128,128,256) f32
// ---------------------------------------------------------------------------

typedef __attribute__((ext_vector_type(8))) short short8v;     // MFMA bf16 frag
typedef __attribute__((ext_vector_type(4))) float f32x4;       // MFMA acc
typedef __attribute__((ext_vector_type(8))) unsigned short ushort8v;
typedef unsigned long long u64;

#define DEV __device__ __forceinline__

DEV unsigned short f2bf(float f) {               // round-to-nearest-even f32->bf16
    union { float f; unsigned u; } v; v.f = f;
    unsigned r = v.u + 0x7FFFu + ((v.u >> 16) & 1u);
    return (unsigned short)(r >> 16);
}

DEV short8v cvt_f32x8(const float4 lo, const float4 hi) {      // 8 f32 -> 8 bf16
    union U { __hip_bfloat162 h[4]; short8v s; } u;
    u.h[0] = __float22bfloat162_rn(float2{lo.x, lo.y});
    u.h[1] = __float22bfloat162_rn(float2{lo.z, lo.w});
    u.h[2] = __float22bfloat162_rn(float2{hi.x, hi.y});
    u.h[3] = __float22bfloat162_rn(float2{hi.z, hi.w});
    return u.s;
}

DEV uint2 pack4(f32x4 v) {                       // 4 f32 -> 4 bf16 (8 B)
    union { __hip_bfloat162 h; unsigned u; } a, b;
    a.h = __float22bfloat162_rn(float2{v[0], v[1]});
    b.h = __float22bfloat162_rn(float2{v[2], v[3]});
    return uint2{a.u, b.u};
}

#define ATT_SCALE 0.17677669529663687f           // 1/sqrt(32)

// ---------------------------------------------------------------------------
// Prep kernels (R2-proven)
// ---------------------------------------------------------------------------
__global__ void prep_weights(const float* __restrict__ Wq, const float* __restrict__ Wkv,
                             const float* __restrict__ Wo,
                             unsigned short* __restrict__ WqT, unsigned short* __restrict__ WkvT,
                             unsigned short* __restrict__ WoT) {
    int idx = blockIdx.x * 256 + threadIdx.x;            // 262144 total
    if (idx < 65536) {
        int n = idx >> 8, k = idx & 255;
        WqT[idx] = f2bf(Wq[k * 256 + n] * ATT_SCALE);
    } else if (idx < 196608) {
        int i = idx - 65536;
        int n = i >> 8, k = i & 255;
        WkvT[i] = f2bf(Wkv[k * 512 + n]);
    } else {
        int i = idx - 196608;
        int n = i >> 8, k = i & 255;
        WoT[i] = f2bf(Wo[k * 256 + n]);
    }
}

__global__ void prep_bias(const float* __restrict__ rel_table, const float* __restrict__ bq,
                          float* __restrict__ biasb, float* __restrict__ bqs) {
    int idx = blockIdx.x * 256 + threadIdx.x;
    if (idx < 131072) {
        int head = idx >> 14;
        int q = (idx >> 6) & 255;
        int k = idx & 63;
        int qi = q >> 4, qj = q & 15;
        int ki = k >> 3, kj = k & 7;
        int r0 = qi - 2 * ki + 14, r1 = qj - 2 * kj + 14;
        biasb[idx] = rel_table[(r0 * 30 + r1) * 8 + head];
    } else if (idx < 131328) {
        int i = idx - 131072;
        bqs[i] = bq[i] * ATT_SCALE;
    }
}

__global__ void prep_mask(const int* __restrict__ mask, u64* __restrict__ mp) {
    int idx = blockIdx.x * 256 + threadIdx.x;            // 131072 rows
    const int4* src = reinterpret_cast<const int4*>(mask + (size_t)idx * 64);
    u64 bits = 0;
#pragma unroll
    for (int c = 0; c < 16; ++c) {
        int4 v = src[c];
        if (v.x) bits |= 1ull << (c * 4 + 0);
        if (v.y) bits |= 1ull << (c * 4 + 1);
        if (v.z) bits |= 1ull << (c * 4 + 2);
        if (v.w) bits |= 1ull << (c * 4 + 3);
    }
    mp[idx] = bits;
}

// ---------------------------------------------------------------------------
// 2-phase counted-vmcnt GEMM, Q-proj (f32 A): Qbuf = x @ Wq(scaled) + bq.
// R14-proven; R15: grid 1024 (128 rows/block, NT=8) -> 3-4 blocks/CU resident
// (48 KB ring each) = up to 24 waves/CU, 3x the independent tile-pipelines.
// vmcnt constants are per-wave-relative: unchanged except last-tile index.
// ---------------------------------------------------------------------------
__global__ __launch_bounds__(512) void gemm_q2(
    const float* __restrict__ A,             // x [131072][256] f32
    const unsigned short* __restrict__ WT,   // WqT [256][256] bf16 (scaled)
    const float* __restrict__ bias,          // bqs [256]
    unsigned short* __restrict__ Cout)       // Qbuf [131072][256] bf16
{
    __shared__ __align__(16) unsigned char R[3][16384];  // ring: 3 x 16 rows x 1KB

    const int tid = threadIdx.x;
    const int w = tid >> 6, lane = tid & 63, lr = lane & 15, lg = lane >> 4;
    const int wn = w * 32;                               // wave's 32-col slice
    const size_t rowbase = (size_t)blockIdx.x * 128;     // grid 1024, 8 tiles
    const int NT = 8;

    // W fragments (64 VGPR, loop-invariant, fits default budget)
    short8v wf[8][2];
#pragma unroll
    for (int kt = 0; kt < 8; ++kt)
#pragma unroll
        for (int nt = 0; nt < 2; ++nt)
            wf[kt][nt] = *reinterpret_cast<const short8v*>(
                WT + (size_t)(wn + nt * 16 + lr) * 256 + kt * 32 + lg * 8);

    const unsigned char* Ab = (const unsigned char*)A;

    auto issue = [&](int t) {                            // 2 loads/wave: rows 2w, 2w+1
        int slot = t % 3;
        size_t g0 = (rowbase + (size_t)t * 16) * 1024;
#pragma unroll
        for (int L = 0; L < 2; ++L) {
            int r = w * 2 + L;                           // row in tile
            int v = lane ^ r;                            // inverse-swizzled 16B unit
            __builtin_amdgcn_global_load_lds(
                (const __attribute__((address_space(1))) void*)
                    (Ab + g0 + (size_t)r * 1024 + (size_t)v * 16),
                (__attribute__((address_space(3))) void*)(&R[slot][r * 1024]),
                16, 0, 0);
        }
    };

    issue(0); issue(1);                                  // prologue: 2 tiles in flight

    for (int t = 0; t < NT; ++t) {
        // wait for OWN tile-t loads: N = exact count of newer vmem ops
        if (t == 0)           asm volatile("s_waitcnt vmcnt(2)" ::: "memory");
        else if (t == 1)      asm volatile("s_waitcnt vmcnt(4)" ::: "memory");
        else if (t == NT - 1) asm volatile("s_waitcnt vmcnt(4)" ::: "memory");
        else                  asm volatile("s_waitcnt vmcnt(6)" ::: "memory");
        __builtin_amdgcn_s_barrier();                    // raw: no vmcnt drain
        __builtin_amdgcn_sched_barrier(0);

        const int slot = t % 3;
        // read f32 tile (swizzled) + convert to bf16 fragments (row lr, all K)
        short8v af[8];
#pragma unroll
        for (int kt = 0; kt < 8; ++kt) {
            int U0 = kt * 8 + lg * 2;
            const unsigned char* base = &R[slot][lr * 1024];
            float4 f0 = *reinterpret_cast<const float4*>(base + ((U0 ^ lr) << 4));
            float4 f1 = *reinterpret_cast<const float4*>(base + (((U0 + 1) ^ lr) << 4));
            af[kt] = cvt_f32x8(f0, f1);
        }
        if (t + 2 < NT) issue(t + 2);                    // prefetch across barrier

        f32x4 acc[2];
        acc[0] = {0.f, 0.f, 0.f, 0.f}; acc[1] = {0.f, 0.f, 0.f, 0.f};
#pragma unroll
        for (int kt = 0; kt < 8; ++kt) {
            acc[0] = __builtin_amdgcn_mfma_f32_16x16x32_bf16(wf[kt][0], af[kt], acc[0], 0, 0, 0);
            acc[1] = __builtin_amdgcn_mfma_f32_16x16x32_bf16(wf[kt][1], af[kt], acc[1], 0, 0, 0);
        }

        size_t row = rowbase + (size_t)t * 16 + lr;      // D[n][m]: m = lr
#pragma unroll
        for (int nt = 0; nt < 2; ++nt) {
            f32x4 b4 = *reinterpret_cast<const f32x4*>(bias + wn + nt * 16 + lg * 4);
            *reinterpret_cast<uint2*>(
                Cout + row * 256 + wn + nt * 16 + lg * 4) = pack4(acc[nt] + b4);
        }
    }
}

// ---------------------------------------------------------------------------
// 2-phase counted-vmcnt GEMM, O-proj (bf16 A): out = attn @ Wo + bo.
// R14-proven; R15: grid 1024 (128 rows/block, NT=8), 24 KB ring -> 4 resident
// blocks/CU = 32 waves (100% occ target).
// ---------------------------------------------------------------------------
__global__ __launch_bounds__(512) void gemm_o2(
    const unsigned short* __restrict__ A,    // [131072][256] bf16 (attn out)
    const unsigned short* __restrict__ WT,   // WoT [256][256] bf16
    const float* __restrict__ bias, float* __restrict__ out)
{
    __shared__ __align__(16) unsigned char R[3][8192];   // ring: 3 x 16 rows x 512B

    const int tid = threadIdx.x;
    const int w = tid >> 6, lane = tid & 63, lr = lane & 15, lg = lane >> 4;
    const int wn = w * 32;
    const size_t rowbase = (size_t)blockIdx.x * 128;     // grid 1024, 8 tiles
    const int NT = 8;

    short8v wf[8][2];
#pragma unroll
    for (int kt = 0; kt < 8; ++kt)
#pragma unroll
        for (int nt = 0; nt < 2; ++nt)
            wf[kt][nt] = *reinterpret_cast<const short8v*>(
                WT + (size_t)(wn + nt * 16 + lr) * 256 + kt * 32 + lg * 8);

    const int r_ = lane >> 5;                 // row parity within 2-row chunk
    const int u_ = lane & 31;                 // 16B unit within row
    const unsigned char* Ab = (const unsigned char*)A;

    auto issue = [&](int t) {                 // 1 load/wave: row 2w+r_
        int slot = t % 3;
        size_t g0 = (rowbase + (size_t)t * 16) * 512;
        int r = 2 * w + r_;
        int v = u_ ^ r;
        __builtin_amdgcn_global_load_lds(
            (const __attribute__((address_space(1))) void*)
                (Ab + g0 + (size_t)r * 512 + (size_t)v * 16),
            (__attribute__((address_space(3))) void*)(&R[slot][w * 1024]),
            16, 0, 0);
    };

    issue(0); issue(1);                       // prologue

    for (int t = 0; t < NT; ++t) {
        if (t == 0)           asm volatile("s_waitcnt vmcnt(1)" ::: "memory");
        else if (t == 1)      asm volatile("s_waitcnt vmcnt(3)" ::: "memory");
        else if (t == NT - 1) asm volatile("s_waitcnt vmcnt(4)" ::: "memory");
        else                  asm volatile("s_waitcnt vmcnt(5)" ::: "memory");
        __builtin_amdgcn_s_barrier();
        __builtin_amdgcn_sched_barrier(0);

        const int slot = t % 3;
        short8v af[8];
#pragma unroll
        for (int kt = 0; kt < 8; ++kt)
            af[kt] = *reinterpret_cast<const short8v*>(
                &R[slot][lr * 512 + (((kt * 4 + lg) ^ lr) << 4)]);
        if (t + 2 < NT) issue(t + 2);

        f32x4 acc[2];
        acc[0] = {0.f, 0.f, 0.f, 0.f}; acc[1] = {0.f, 0.f, 0.f, 0.f};
#pragma unroll
        for (int kt = 0; kt < 8; ++kt) {
            acc[0] = __builtin_amdgcn_mfma_f32_16x16x32_bf16(wf[kt][0], af[kt], acc[0], 0, 0, 0);
            acc[1] = __builtin_amdgcn_mfma_f32_16x16x32_bf16(wf[kt][1], af[kt], acc[1], 0, 0, 0);
        }

        size_t row = rowbase + (size_t)t * 16 + lr;
#pragma unroll
        for (int nt = 0; nt < 2; ++nt) {
            f32x4 b4 = *reinterpret_cast<const f32x4*>(bias + wn + nt * 16 + lg * 4);
            *reinterpret_cast<f32x4*>(out + row * 256 + wn + nt * 16 + lg * 4)
                = acc[nt] + b4;
        }
    }
}

// ---------------------------------------------------------------------------
// KV-proj GEMM (R3-proven double-buffered gemm_proj, f32-A, bf16 out).
// ---------------------------------------------------------------------------
template <bool AF32, bool OUT_BF16>
__global__ __launch_bounds__(256) void gemm_proj(
    const void* __restrict__ Ain, const unsigned short* __restrict__ BT,
    const float* __restrict__ bias, void* __restrict__ Cout,
    int M, int N, int K)
{
    __shared__ __align__(16) unsigned char As[2][8192];
    __shared__ __align__(16) unsigned char Bs[2][8192];
    const float* Af = (const float*)Ain;

    const int tid = threadIdx.x;
    const int mb = blockIdx.y * 128, nb = blockIdx.x * 128;
    const int w = tid >> 6, lane = tid & 63, lr = lane & 15, lg = lane >> 4;
    const int wm = (w >> 1) * 64, wn = (w & 1) * 64;

    const int cr0 = (w << 5) + (lane >> 2);
    const int csp = lane & 3;
    const int cs0 = csp ^ ((cr0 >> 1) & 3);
    const int cs1 = csp ^ (((cr0 + 16) >> 1) & 3);

    auto stageB = [&](int buf, int kb) {
        __builtin_amdgcn_global_load_lds(
            (const __attribute__((address_space(1))) void*)(BT + (size_t)(nb + cr0) * K + kb + cs0 * 8),
            (__attribute__((address_space(3))) void*)(&Bs[buf][w << 11]), 16, 0, 0);
        __builtin_amdgcn_global_load_lds(
            (const __attribute__((address_space(1))) void*)(BT + (size_t)(nb + cr0 + 16) * K + kb + cs1 * 8),
            (__attribute__((address_space(3))) void*)(&Bs[buf][(w << 11) + 1024]), 16, 0, 0);
    };

    float4 areg[2][2];
    auto loadA = [&](int kb) {
#pragma unroll
        for (int i = 0; i < 2; ++i) {
            int flat = tid + (i << 8);
            int r = flat >> 2, sp = flat & 3;
            int s = sp ^ ((r >> 1) & 3);
            const float* src = Af + (size_t)(mb + r) * K + kb + s * 8;
            areg[i][0] = *reinterpret_cast<const float4*>(src);
            areg[i][1] = *reinterpret_cast<const float4*>(src + 4);
        }
    };
    auto writeA = [&](int buf) {
#pragma unroll
        for (int i = 0; i < 2; ++i) {
            int flat = tid + (i << 8);
            int r = flat >> 2, sp = flat & 3;
            ushort8v u = { f2bf(areg[i][0].x), f2bf(areg[i][0].y),
                           f2bf(areg[i][0].z), f2bf(areg[i][0].w),
                           f2bf(areg[i][1].x), f2bf(areg[i][1].y),
                           f2bf(areg[i][1].z), f2bf(areg[i][1].w) };
            *reinterpret_cast<ushort8v*>(&As[buf][r * 64 + sp * 16]) = u;
        }
    };
    auto rdA = [&](int buf, int row) -> short8v {
        int swz = (lg ^ ((row >> 1) & 3)) << 4;
        return *reinterpret_cast<const short8v*>(&As[buf][row * 64 + swz]);
    };
    auto rdB = [&](int buf, int row) -> short8v {
        int swz = (lg ^ ((row >> 1) & 3)) << 4;
        return *reinterpret_cast<const short8v*>(&Bs[buf][row * 64 + swz]);
    };

    f32x4 acc[4][4];
#pragma unroll
    for (int i = 0; i < 4; ++i)
#pragma unroll
        for (int j = 0; j < 4; ++j) acc[i][j] = {0.f, 0.f, 0.f, 0.f};

    loadA(0); stageB(0, 0); writeA(0);
    __syncthreads();

    const int NT = K >> 5;
    int cur = 0;
    for (int t = 0; t < NT; ++t) {
        if (t + 1 < NT) { loadA((t + 1) << 5); stageB(cur ^ 1, (t + 1) << 5); }
        short8v af[4], bfr[4];
#pragma unroll
        for (int mt = 0; mt < 4; ++mt) af[mt] = rdA(cur, wm + mt * 16 + lr);
#pragma unroll
        for (int nt = 0; nt < 4; ++nt) bfr[nt] = rdB(cur, wn + nt * 16 + lr);
#pragma unroll
        for (int mt = 0; mt < 4; ++mt)
#pragma unroll
            for (int nt = 0; nt < 4; ++nt)
                acc[mt][nt] = __builtin_amdgcn_mfma_f32_16x16x32_bf16(
                    af[mt], bfr[nt], acc[mt][nt], 0, 0, 0);
        if (t + 1 < NT) writeA(cur ^ 1);
        __syncthreads();
        cur ^= 1;
    }

#pragma unroll
    for (int mt = 0; mt < 4; ++mt)
#pragma unroll
        for (int nt = 0; nt < 4; ++nt)
#pragma unroll
            for (int j = 0; j < 4; ++j) {
                int row = mb + wm + mt * 16 + lg * 4 + j;
                int col = nb + wn + nt * 16 + lr;
                float v = acc[mt][nt][j] + bias[col];
                if constexpr (OUT_BF16)
                    ((unsigned short*)Cout)[(size_t)row * N + col] = f2bf(v);
                else
                    ((float*)Cout)[(size_t)row * N + col] = v;
            }
}

// ---------------------------------------------------------------------------
// Fused window attention (R1/R2-proven, verbatim).
// ---------------------------------------------------------------------------
__global__ __launch_bounds__(256) void win_attn(
    unsigned short* __restrict__ Qbuf,            // [8*128*128, 256] bf16 (in/out)
    const unsigned short* __restrict__ KVbuf,     // [8*64*64, 512] bf16
    const u64* __restrict__ maskp,                // [8][64][256] packed bits
    const float* __restrict__ biasb)              // [8][256][64]
{
    __shared__ __align__(16) unsigned char Pb[256 * 128];   // P, 64-wide XOR-swizzled
    __shared__ __align__(16) unsigned short Vt[32][72];     // V^T: [dk][key]

    const int tid = threadIdx.x;
    const int win = blockIdx.x, head = blockIdx.y, b = blockIdx.z;
    const int wi = win >> 3, wj = win & 7;
    const int w = tid >> 6, lane = tid & 63, lr = lane & 15, lg = lane >> 4;
    const int qb = w * 64;

    {
        int key = tid & 63, c = tid >> 6;
        int kr = (wi * 8 + (key >> 3) + 4) & 63;
        int kc = (wj * 8 + (key & 7) + 4) & 63;
        ushort8v v = *reinterpret_cast<const ushort8v*>(
            KVbuf + ((size_t)(b * 4096 + kr * 64 + kc)) * 512 + 256 + head * 32 + c * 8);
#pragma unroll
        for (int e = 0; e < 8; ++e) Vt[c * 8 + e][key] = v[e];
    }

    short8v qf[4], kf[4];
#pragma unroll
    for (int mt = 0; mt < 4; ++mt) {
        int q = qb + mt * 16 + lr;
        int gr = (wi * 16 + (q >> 4) + 8) & 127;
        int gc = (wj * 16 + (q & 15) + 8) & 127;
        qf[mt] = *reinterpret_cast<const short8v*>(
            Qbuf + ((size_t)(b * 16384 + gr * 128 + gc)) * 256 + head * 32 + lg * 8);
    }
#pragma unroll
    for (int nt = 0; nt < 4; ++nt) {
        int key = nt * 16 + lr;
        int kr = (wi * 8 + (key >> 3) + 4) & 63;
        int kc = (wj * 8 + (key & 7) + 4) & 63;
        kf[nt] = *reinterpret_cast<const short8v*>(
            KVbuf + ((size_t)(b * 4096 + kr * 64 + kc)) * 512 + head * 32 + lg * 8);
    }

    f32x4 s[4][4];
#pragma unroll
    for (int mt = 0; mt < 4; ++mt)
#pragma unroll
        for (int nt = 0; nt < 4; ++nt) s[mt][nt] = {0.f, 0.f, 0.f, 0.f};
    __builtin_amdgcn_s_setprio(1);
#pragma unroll
    for (int mt = 0; mt < 4; ++mt)
#pragma unroll
        for (int nt = 0; nt < 4; ++nt)
            s[mt][nt] = __builtin_amdgcn_mfma_f32_16x16x32_bf16(qf[mt], kf[nt], s[mt][nt], 0, 0, 0);
    __builtin_amdgcn_s_setprio(0);

    const u64* mrow = maskp + (size_t)(head * 64 + win) * 256;
#pragma unroll
    for (int mt = 0; mt < 4; ++mt) {
#pragma unroll
        for (int j = 0; j < 4; ++j) {
            int q = qb + mt * 16 + lg * 4 + j;
            u64 mb = mrow[q];
            const float* brow = biasb + (size_t)(head * 256 + q) * 64;
            float v[4];
            float m = -3.0e38f;
#pragma unroll
            for (int nt = 0; nt < 4; ++nt) {
                int key = nt * 16 + lr;
                float sv = s[mt][nt][j] + brow[key];
                if ((mb >> key) & 1ull) sv = -1.0e9f;
                v[nt] = sv;
                m = fmaxf(m, sv);
            }
#pragma unroll
            for (int d = 1; d < 16; d <<= 1) m = fmaxf(m, __shfl_xor(m, d, 64));
            float sum = 0.f;
#pragma unroll
            for (int nt = 0; nt < 4; ++nt) { v[nt] = __expf(v[nt] - m); sum += v[nt]; }
#pragma unroll
            for (int d = 1; d < 16; d <<= 1) sum += __shfl_xor(sum, d, 64);
            float inv = 1.0f / sum;
            int sw = (q & 7) << 4;
#pragma unroll
            for (int nt = 0; nt < 4; ++nt) {
                int off = q * 128 + (((nt * 16 + lr) * 2) ^ sw);
                *reinterpret_cast<unsigned short*>(Pb + off) = f2bf(v[nt] * inv);
            }
        }
    }

    __syncthreads();

    f32x4 o[4][2];
#pragma unroll
    for (int mt = 0; mt < 4; ++mt)
#pragma unroll
        for (int nt = 0; nt < 2; ++nt) o[mt][nt] = {0.f, 0.f, 0.f, 0.f};
#pragma unroll
    for (int kc = 0; kc < 2; ++kc) {
        short8v pf[4], vf[2];
#pragma unroll
        for (int mt = 0; mt < 4; ++mt) {
            int row = qb + mt * 16 + lr;
            int coff = (kc * 64 + lg * 16) ^ ((row & 7) << 4);
            pf[mt] = *reinterpret_cast<const short8v*>(Pb + row * 128 + coff);
        }
#pragma unroll
        for (int nt = 0; nt < 2; ++nt)
            vf[nt] = *reinterpret_cast<const short8v*>(&Vt[nt * 16 + lr][kc * 32 + lg * 8]);
        __builtin_amdgcn_s_setprio(1);
#pragma unroll
        for (int mt = 0; mt < 4; ++mt)
#pragma unroll
            for (int nt = 0; nt < 2; ++nt)
                o[mt][nt] = __builtin_amdgcn_mfma_f32_16x16x32_bf16(pf[mt], vf[nt], o[mt][nt], 0, 0, 0);
        __builtin_amdgcn_s_setprio(0);
    }

#pragma unroll
    for (int mt = 0; mt < 4; ++mt)
#pragma unroll
        for (int j = 0; j < 4; ++j) {
            int q = qb + mt * 16 + lg * 4 + j;
            int gr = (wi * 16 + (q >> 4) + 8) & 127;
            int gc = (wj * 16 + (q & 15) + 8) & 127;
            unsigned short* dst =
                Qbuf + ((size_t)(b * 16384 + gr * 128 + gc)) * 256 + head * 32;
#pragma unroll
            for (int nt = 0; nt < 2; ++nt)
                dst[nt * 16 + lr] = f2bf(o[mt][nt][j]);
        }
}

// ---------------------------------------------------------------------------
extern "C" void kernel_launch(void* const* d_in, const int* in_sizes, int n_in,
                              void* d_out, int out_size, void* d_ws, size_t ws_size,
                              hipStream_t stream) {
    const float* x    = (const float*)d_in[0];
    const float* z    = (const float*)d_in[1];
    const int*   mask = (const int*)d_in[2];
    const float* Wq   = (const float*)d_in[3];
    const float* bq   = (const float*)d_in[4];
    const float* Wkv  = (const float*)d_in[5];
    const float* bkv  = (const float*)d_in[6];
    const float* Wo   = (const float*)d_in[7];
    const float* bo   = (const float*)d_in[8];
    const float* rel  = (const float*)d_in[9];
    float* out = (float*)d_out;

    // workspace layout (~103 MB, R2-identical)
    char* ws = (char*)d_ws;
    unsigned short* Qbuf  = (unsigned short*)(ws);                 // 67,108,864 B
    unsigned short* KVbuf = (unsigned short*)(ws + 67108864);      // 33,554,432 B
    unsigned short* WqT   = (unsigned short*)(ws + 100663296);     //    131,072 B
    unsigned short* WkvT  = (unsigned short*)(ws + 100794368);     //    262,144 B
    unsigned short* WoT   = (unsigned short*)(ws + 101056512);     //    131,072 B
    float*          biasb = (float*)(ws + 101187584);              //    524,288 B
    u64*            maskp = (u64*)(ws + 101711872);                //  1,048,576 B
    float*          bqs   = (float*)(ws + 102760448);              //      1,024 B

    prep_weights<<<1024, 256, 0, stream>>>(Wq, Wkv, Wo, WqT, WkvT, WoT);
    prep_bias<<<513, 256, 0, stream>>>(rel, bq, biasb, bqs);
    prep_mask<<<512, 256, 0, stream>>>(mask, maskp);

    // Q = x @ (Wq*scale) + bq*scale -> bf16 [131072, 256]  (2-phase counted)
    gemm_q2<<<1024, 512, 0, stream>>>(x, WqT, bqs, Qbuf);
    // KV = z @ Wkv + bkv -> bf16 [32768, 512]
    gemm_proj<true, true><<<dim3(4, 256), 256, 0, stream>>>(
        (const void*)z, WkvT, bkv, (void*)KVbuf, 32768, 512, 256);
    // fused window attention (in-place into Qbuf)
    win_attn<<<dim3(64, 8, 8), 256, 0, stream>>>(Qbuf, KVbuf, maskp, biasb);
    // out = attn @ Wo + bo -> f32  (2-phase counted)
    gemm_o2<<<1024, 512, 0, stream>>>(Qbuf, WoT, bo, out);
}

// Round 16
// 208.355 us; speedup vs baseline: 1.0386x; 1.0386x over previous
//
#include <hip/hip_runtime.h>
#include <hip/hip_bf16.h>
#include <type_traits>

// ---------------------------------------------------------------------------
// Problem constants
//   x: (8,128,128,256) f32   z: (8,64,64,256) f32   mask: (1,8,8,8,256,64) int
//   Wq (256,256) bq(256)  Wkv (256,512) bkv(512)  Wo (256,256) bo(256)
//   rel_table (900,8) f32   out: (8,128,128,256) f32
// Final configuration (R14, measured 208.6 us):
//   prep kernels -> gemm_q2 (2-phase counted-vmcnt, grid 512) -> gemm_proj
//   (KV) -> win_attn -> gemm_o2 (2-phase counted-vmcnt, grid 512)
// ---------------------------------------------------------------------------

typedef __attribute__((ext_vector_type(8))) short short8v;     // MFMA bf16 frag
typedef __attribute__((ext_vector_type(4))) float f32x4;       // MFMA acc
typedef __attribute__((ext_vector_type(8))) unsigned short ushort8v;
typedef unsigned long long u64;

#define DEV __device__ __forceinline__

DEV unsigned short f2bf(float f) {               // round-to-nearest-even f32->bf16
    union { float f; unsigned u; } v; v.f = f;
    unsigned r = v.u + 0x7FFFu + ((v.u >> 16) & 1u);
    return (unsigned short)(r >> 16);
}

DEV short8v cvt_f32x8(const float4 lo, const float4 hi) {      // 8 f32 -> 8 bf16
    union U { __hip_bfloat162 h[4]; short8v s; } u;
    u.h[0] = __float22bfloat162_rn(float2{lo.x, lo.y});
    u.h[1] = __float22bfloat162_rn(float2{lo.z, lo.w});
    u.h[2] = __float22bfloat162_rn(float2{hi.x, hi.y});
    u.h[3] = __float22bfloat162_rn(float2{hi.z, hi.w});
    return u.s;
}

DEV uint2 pack4(f32x4 v) {                       // 4 f32 -> 4 bf16 (8 B)
    union { __hip_bfloat162 h; unsigned u; } a, b;
    a.h = __float22bfloat162_rn(float2{v[0], v[1]});
    b.h = __float22bfloat162_rn(float2{v[2], v[3]});
    return uint2{a.u, b.u};
}

#define ATT_SCALE 0.17677669529663687f           // 1/sqrt(32)

// ---------------------------------------------------------------------------
// Prep kernels (R2-proven)
// ---------------------------------------------------------------------------
__global__ void prep_weights(const float* __restrict__ Wq, const float* __restrict__ Wkv,
                             const float* __restrict__ Wo,
                             unsigned short* __restrict__ WqT, unsigned short* __restrict__ WkvT,
                             unsigned short* __restrict__ WoT) {
    int idx = blockIdx.x * 256 + threadIdx.x;            // 262144 total
    if (idx < 65536) {
        int n = idx >> 8, k = idx & 255;
        WqT[idx] = f2bf(Wq[k * 256 + n] * ATT_SCALE);
    } else if (idx < 196608) {
        int i = idx - 65536;
        int n = i >> 8, k = i & 255;
        WkvT[i] = f2bf(Wkv[k * 512 + n]);
    } else {
        int i = idx - 196608;
        int n = i >> 8, k = i & 255;
        WoT[i] = f2bf(Wo[k * 256 + n]);
    }
}

__global__ void prep_bias(const float* __restrict__ rel_table, const float* __restrict__ bq,
                          float* __restrict__ biasb, float* __restrict__ bqs) {
    int idx = blockIdx.x * 256 + threadIdx.x;
    if (idx < 131072) {
        int head = idx >> 14;
        int q = (idx >> 6) & 255;
        int k = idx & 63;
        int qi = q >> 4, qj = q & 15;
        int ki = k >> 3, kj = k & 7;
        int r0 = qi - 2 * ki + 14, r1 = qj - 2 * kj + 14;
        biasb[idx] = rel_table[(r0 * 30 + r1) * 8 + head];
    } else if (idx < 131328) {
        int i = idx - 131072;
        bqs[i] = bq[i] * ATT_SCALE;
    }
}

__global__ void prep_mask(const int* __restrict__ mask, u64* __restrict__ mp) {
    int idx = blockIdx.x * 256 + threadIdx.x;            // 131072 rows
    const int4* src = reinterpret_cast<const int4*>(mask + (size_t)idx * 64);
    u64 bits = 0;
#pragma unroll
    for (int c = 0; c < 16; ++c) {
        int4 v = src[c];
        if (v.x) bits |= 1ull << (c * 4 + 0);
        if (v.y) bits |= 1ull << (c * 4 + 1);
        if (v.z) bits |= 1ull << (c * 4 + 2);
        if (v.w) bits |= 1ull << (c * 4 + 3);
    }
    mp[idx] = bits;
}

// ---------------------------------------------------------------------------
// 2-phase counted-vmcnt GEMM, Q-proj (f32 A): Qbuf = x @ Wq(scaled) + bq.
// 512 thr / 8 waves, each wave owns n-slice 32 (wf[8][2] = 64 VGPR, stays
// register-resident under the 128-VGPR default). Block-shared A-tile ring:
// 3 slots x 16 rows x 1KB f32 = 48 KB. Staging split across waves (2 x 1KB
// global_load_lds each, zero redundancy). Sync per tile: wait OWN loads via
// counted vmcnt (N = exact count of newer vmem ops) THEN raw s_barrier ->
// tile t+1's loads stay in flight across the barrier (never drains to 0).
// Source-XOR swizzle v=lane^r (self-inverse read map).
// ---------------------------------------------------------------------------
__global__ __launch_bounds__(512) void gemm_q2(
    const float* __restrict__ A,             // x [131072][256] f32
    const unsigned short* __restrict__ WT,   // WqT [256][256] bf16 (scaled)
    const float* __restrict__ bias,          // bqs [256]
    unsigned short* __restrict__ Cout)       // Qbuf [131072][256] bf16
{
    __shared__ __align__(16) unsigned char R[3][16384];  // ring: 3 x 16 rows x 1KB

    const int tid = threadIdx.x;
    const int w = tid >> 6, lane = tid & 63, lr = lane & 15, lg = lane >> 4;
    const int wn = w * 32;                               // wave's 32-col slice
    const size_t rowbase = (size_t)blockIdx.x * 256;     // grid 512, NT=16

    // W fragments (64 VGPR, loop-invariant, fits default budget)
    short8v wf[8][2];
#pragma unroll
    for (int kt = 0; kt < 8; ++kt)
#pragma unroll
        for (int nt = 0; nt < 2; ++nt)
            wf[kt][nt] = *reinterpret_cast<const short8v*>(
                WT + (size_t)(wn + nt * 16 + lr) * 256 + kt * 32 + lg * 8);

    const unsigned char* Ab = (const unsigned char*)A;

    auto issue = [&](int t) {                            // 2 loads/wave: rows 2w, 2w+1
        int slot = t % 3;
        size_t g0 = (rowbase + (size_t)t * 16) * 1024;
#pragma unroll
        for (int L = 0; L < 2; ++L) {
            int r = w * 2 + L;                           // row in tile
            int v = lane ^ r;                            // inverse-swizzled 16B unit
            __builtin_amdgcn_global_load_lds(
                (const __attribute__((address_space(1))) void*)
                    (Ab + g0 + (size_t)r * 1024 + (size_t)v * 16),
                (__attribute__((address_space(3))) void*)(&R[slot][r * 1024]),
                16, 0, 0);
        }
    };

    issue(0); issue(1);                                  // prologue: 2 tiles in flight

    for (int t = 0; t < 16; ++t) {
        // wait for OWN tile-t loads: N = exact count of newer vmem ops
        if (t == 0)       asm volatile("s_waitcnt vmcnt(2)" ::: "memory");
        else if (t == 1)  asm volatile("s_waitcnt vmcnt(4)" ::: "memory");
        else if (t == 15) asm volatile("s_waitcnt vmcnt(4)" ::: "memory");
        else              asm volatile("s_waitcnt vmcnt(6)" ::: "memory");
        __builtin_amdgcn_s_barrier();                    // raw: no vmcnt drain
        __builtin_amdgcn_sched_barrier(0);

        const int slot = t % 3;
        // read f32 tile (swizzled) + convert to bf16 fragments (row lr, all K)
        short8v af[8];
#pragma unroll
        for (int kt = 0; kt < 8; ++kt) {
            int U0 = kt * 8 + lg * 2;
            const unsigned char* base = &R[slot][lr * 1024];
            float4 f0 = *reinterpret_cast<const float4*>(base + ((U0 ^ lr) << 4));
            float4 f1 = *reinterpret_cast<const float4*>(base + (((U0 + 1) ^ lr) << 4));
            af[kt] = cvt_f32x8(f0, f1);
        }
        if (t + 2 < 16) issue(t + 2);                    // prefetch across barrier

        f32x4 acc[2];
        acc[0] = {0.f, 0.f, 0.f, 0.f}; acc[1] = {0.f, 0.f, 0.f, 0.f};
#pragma unroll
        for (int kt = 0; kt < 8; ++kt) {
            acc[0] = __builtin_amdgcn_mfma_f32_16x16x32_bf16(wf[kt][0], af[kt], acc[0], 0, 0, 0);
            acc[1] = __builtin_amdgcn_mfma_f32_16x16x32_bf16(wf[kt][1], af[kt], acc[1], 0, 0, 0);
        }

        size_t row = rowbase + (size_t)t * 16 + lr;      // D[n][m]: m = lr
#pragma unroll
        for (int nt = 0; nt < 2; ++nt) {
            f32x4 b4 = *reinterpret_cast<const f32x4*>(bias + wn + nt * 16 + lg * 4);
            *reinterpret_cast<uint2*>(
                Cout + row * 256 + wn + nt * 16 + lg * 4) = pack4(acc[nt] + b4);
        }
    }
}

// ---------------------------------------------------------------------------
// 2-phase counted-vmcnt GEMM, O-proj (bf16 A): out = attn @ Wo + bo.
// Same template; bf16 tile = 16 rows x 512 B, ring 3 x 8 KB = 24 KB.
// 1 load/wave/tile (rows 2w+(lane>>5)), 2 f32x4 stores/iter.
// vmcnt N: t=0 ->1, t=1 ->3, steady ->5, t=15 ->4.
// ---------------------------------------------------------------------------
__global__ __launch_bounds__(512) void gemm_o2(
    const unsigned short* __restrict__ A,    // [131072][256] bf16 (attn out)
    const unsigned short* __restrict__ WT,   // WoT [256][256] bf16
    const float* __restrict__ bias, float* __restrict__ out)
{
    __shared__ __align__(16) unsigned char R[3][8192];   // ring: 3 x 16 rows x 512B

    const int tid = threadIdx.x;
    const int w = tid >> 6, lane = tid & 63, lr = lane & 15, lg = lane >> 4;
    const int wn = w * 32;
    const size_t rowbase = (size_t)blockIdx.x * 256;     // grid 512, NT=16

    short8v wf[8][2];
#pragma unroll
    for (int kt = 0; kt < 8; ++kt)
#pragma unroll
        for (int nt = 0; nt < 2; ++nt)
            wf[kt][nt] = *reinterpret_cast<const short8v*>(
                WT + (size_t)(wn + nt * 16 + lr) * 256 + kt * 32 + lg * 8);

    const int r_ = lane >> 5;                 // row parity within 2-row chunk
    const int u_ = lane & 31;                 // 16B unit within row
    const unsigned char* Ab = (const unsigned char*)A;

    auto issue = [&](int t) {                 // 1 load/wave: row 2w+r_
        int slot = t % 3;
        size_t g0 = (rowbase + (size_t)t * 16) * 512;
        int r = 2 * w + r_;
        int v = u_ ^ r;
        __builtin_amdgcn_global_load_lds(
            (const __attribute__((address_space(1))) void*)
                (Ab + g0 + (size_t)r * 512 + (size_t)v * 16),
            (__attribute__((address_space(3))) void*)(&R[slot][w * 1024]),
            16, 0, 0);
    };

    issue(0); issue(1);                       // prologue

    for (int t = 0; t < 16; ++t) {
        if (t == 0)       asm volatile("s_waitcnt vmcnt(1)" ::: "memory");
        else if (t == 1)  asm volatile("s_waitcnt vmcnt(3)" ::: "memory");
        else if (t == 15) asm volatile("s_waitcnt vmcnt(4)" ::: "memory");
        else              asm volatile("s_waitcnt vmcnt(5)" ::: "memory");
        __builtin_amdgcn_s_barrier();
        __builtin_amdgcn_sched_barrier(0);

        const int slot = t % 3;
        short8v af[8];
#pragma unroll
        for (int kt = 0; kt < 8; ++kt)
            af[kt] = *reinterpret_cast<const short8v*>(
                &R[slot][lr * 512 + (((kt * 4 + lg) ^ lr) << 4)]);
        if (t + 2 < 16) issue(t + 2);

        f32x4 acc[2];
        acc[0] = {0.f, 0.f, 0.f, 0.f}; acc[1] = {0.f, 0.f, 0.f, 0.f};
#pragma unroll
        for (int kt = 0; kt < 8; ++kt) {
            acc[0] = __builtin_amdgcn_mfma_f32_16x16x32_bf16(wf[kt][0], af[kt], acc[0], 0, 0, 0);
            acc[1] = __builtin_amdgcn_mfma_f32_16x16x32_bf16(wf[kt][1], af[kt], acc[1], 0, 0, 0);
        }

        size_t row = rowbase + (size_t)t * 16 + lr;
#pragma unroll
        for (int nt = 0; nt < 2; ++nt) {
            f32x4 b4 = *reinterpret_cast<const f32x4*>(bias + wn + nt * 16 + lg * 4);
            *reinterpret_cast<f32x4*>(out + row * 256 + wn + nt * 16 + lg * 4)
                = acc[nt] + b4;
        }
    }
}

// ---------------------------------------------------------------------------
// KV-proj GEMM (R3-proven double-buffered gemm_proj, f32-A, bf16 out).
// ---------------------------------------------------------------------------
template <bool AF32, bool OUT_BF16>
__global__ __launch_bounds__(256) void gemm_proj(
    const void* __restrict__ Ain, const unsigned short* __restrict__ BT,
    const float* __restrict__ bias, void* __restrict__ Cout,
    int M, int N, int K)
{
    __shared__ __align__(16) unsigned char As[2][8192];
    __shared__ __align__(16) unsigned char Bs[2][8192];
    const float* Af = (const float*)Ain;

    const int tid = threadIdx.x;
    const int mb = blockIdx.y * 128, nb = blockIdx.x * 128;
    const int w = tid >> 6, lane = tid & 63, lr = lane & 15, lg = lane >> 4;
    const int wm = (w >> 1) * 64, wn = (w & 1) * 64;

    const int cr0 = (w << 5) + (lane >> 2);
    const int csp = lane & 3;
    const int cs0 = csp ^ ((cr0 >> 1) & 3);
    const int cs1 = csp ^ (((cr0 + 16) >> 1) & 3);

    auto stageB = [&](int buf, int kb) {
        __builtin_amdgcn_global_load_lds(
            (const __attribute__((address_space(1))) void*)(BT + (size_t)(nb + cr0) * K + kb + cs0 * 8),
            (__attribute__((address_space(3))) void*)(&Bs[buf][w << 11]), 16, 0, 0);
        __builtin_amdgcn_global_load_lds(
            (const __attribute__((address_space(1))) void*)(BT + (size_t)(nb + cr0 + 16) * K + kb + cs1 * 8),
            (__attribute__((address_space(3))) void*)(&Bs[buf][(w << 11) + 1024]), 16, 0, 0);
    };

    float4 areg[2][2];
    auto loadA = [&](int kb) {
#pragma unroll
        for (int i = 0; i < 2; ++i) {
            int flat = tid + (i << 8);
            int r = flat >> 2, sp = flat & 3;
            int s = sp ^ ((r >> 1) & 3);
            const float* src = Af + (size_t)(mb + r) * K + kb + s * 8;
            areg[i][0] = *reinterpret_cast<const float4*>(src);
            areg[i][1] = *reinterpret_cast<const float4*>(src + 4);
        }
    };
    auto writeA = [&](int buf) {
#pragma unroll
        for (int i = 0; i < 2; ++i) {
            int flat = tid + (i << 8);
            int r = flat >> 2, sp = flat & 3;
            ushort8v u = { f2bf(areg[i][0].x), f2bf(areg[i][0].y),
                           f2bf(areg[i][0].z), f2bf(areg[i][0].w),
                           f2bf(areg[i][1].x), f2bf(areg[i][1].y),
                           f2bf(areg[i][1].z), f2bf(areg[i][1].w) };
            *reinterpret_cast<ushort8v*>(&As[buf][r * 64 + sp * 16]) = u;
        }
    };
    auto rdA = [&](int buf, int row) -> short8v {
        int swz = (lg ^ ((row >> 1) & 3)) << 4;
        return *reinterpret_cast<const short8v*>(&As[buf][row * 64 + swz]);
    };
    auto rdB = [&](int buf, int row) -> short8v {
        int swz = (lg ^ ((row >> 1) & 3)) << 4;
        return *reinterpret_cast<const short8v*>(&Bs[buf][row * 64 + swz]);
    };

    f32x4 acc[4][4];
#pragma unroll
    for (int i = 0; i < 4; ++i)
#pragma unroll
        for (int j = 0; j < 4; ++j) acc[i][j] = {0.f, 0.f, 0.f, 0.f};

    loadA(0); stageB(0, 0); writeA(0);
    __syncthreads();

    const int NT = K >> 5;
    int cur = 0;
    for (int t = 0; t < NT; ++t) {
        if (t + 1 < NT) { loadA((t + 1) << 5); stageB(cur ^ 1, (t + 1) << 5); }
        short8v af[4], bfr[4];
#pragma unroll
        for (int mt = 0; mt < 4; ++mt) af[mt] = rdA(cur, wm + mt * 16 + lr);
#pragma unroll
        for (int nt = 0; nt < 4; ++nt) bfr[nt] = rdB(cur, wn + nt * 16 + lr);
#pragma unroll
        for (int mt = 0; mt < 4; ++mt)
#pragma unroll
            for (int nt = 0; nt < 4; ++nt)
                acc[mt][nt] = __builtin_amdgcn_mfma_f32_16x16x32_bf16(
                    af[mt], bfr[nt], acc[mt][nt], 0, 0, 0);
        if (t + 1 < NT) writeA(cur ^ 1);
        __syncthreads();
        cur ^= 1;
    }

#pragma unroll
    for (int mt = 0; mt < 4; ++mt)
#pragma unroll
        for (int nt = 0; nt < 4; ++nt)
#pragma unroll
            for (int j = 0; j < 4; ++j) {
                int row = mb + wm + mt * 16 + lg * 4 + j;
                int col = nb + wn + nt * 16 + lr;
                float v = acc[mt][nt][j] + bias[col];
                if constexpr (OUT_BF16)
                    ((unsigned short*)Cout)[(size_t)row * N + col] = f2bf(v);
                else
                    ((float*)Cout)[(size_t)row * N + col] = v;
            }
}

// ---------------------------------------------------------------------------
// Fused window attention (R1/R2-proven, verbatim).
// ---------------------------------------------------------------------------
__global__ __launch_bounds__(256) void win_attn(
    unsigned short* __restrict__ Qbuf,            // [8*128*128, 256] bf16 (in/out)
    const unsigned short* __restrict__ KVbuf,     // [8*64*64, 512] bf16
    const u64* __restrict__ maskp,                // [8][64][256] packed bits
    const float* __restrict__ biasb)              // [8][256][64]
{
    __shared__ __align__(16) unsigned char Pb[256 * 128];   // P, 64-wide XOR-swizzled
    __shared__ __align__(16) unsigned short Vt[32][72];     // V^T: [dk][key]

    const int tid = threadIdx.x;
    const int win = blockIdx.x, head = blockIdx.y, b = blockIdx.z;
    const int wi = win >> 3, wj = win & 7;
    const int w = tid >> 6, lane = tid & 63, lr = lane & 15, lg = lane >> 4;
    const int qb = w * 64;

    {
        int key = tid & 63, c = tid >> 6;
        int kr = (wi * 8 + (key >> 3) + 4) & 63;
        int kc = (wj * 8 + (key & 7) + 4) & 63;
        ushort8v v = *reinterpret_cast<const ushort8v*>(
            KVbuf + ((size_t)(b * 4096 + kr * 64 + kc)) * 512 + 256 + head * 32 + c * 8);
#pragma unroll
        for (int e = 0; e < 8; ++e) Vt[c * 8 + e][key] = v[e];
    }

    short8v qf[4], kf[4];
#pragma unroll
    for (int mt = 0; mt < 4; ++mt) {
        int q = qb + mt * 16 + lr;
        int gr = (wi * 16 + (q >> 4) + 8) & 127;
        int gc = (wj * 16 + (q & 15) + 8) & 127;
        qf[mt] = *reinterpret_cast<const short8v*>(
            Qbuf + ((size_t)(b * 16384 + gr * 128 + gc)) * 256 + head * 32 + lg * 8);
    }
#pragma unroll
    for (int nt = 0; nt < 4; ++nt) {
        int key = nt * 16 + lr;
        int kr = (wi * 8 + (key >> 3) + 4) & 63;
        int kc = (wj * 8 + (key & 7) + 4) & 63;
        kf[nt] = *reinterpret_cast<const short8v*>(
            KVbuf + ((size_t)(b * 4096 + kr * 64 + kc)) * 512 + head * 32 + lg * 8);
    }

    f32x4 s[4][4];
#pragma unroll
    for (int mt = 0; mt < 4; ++mt)
#pragma unroll
        for (int nt = 0; nt < 4; ++nt) s[mt][nt] = {0.f, 0.f, 0.f, 0.f};
    __builtin_amdgcn_s_setprio(1);
#pragma unroll
    for (int mt = 0; mt < 4; ++mt)
#pragma unroll
        for (int nt = 0; nt < 4; ++nt)
            s[mt][nt] = __builtin_amdgcn_mfma_f32_16x16x32_bf16(qf[mt], kf[nt], s[mt][nt], 0, 0, 0);
    __builtin_amdgcn_s_setprio(0);

    const u64* mrow = maskp + (size_t)(head * 64 + win) * 256;
#pragma unroll
    for (int mt = 0; mt < 4; ++mt) {
#pragma unroll
        for (int j = 0; j < 4; ++j) {
            int q = qb + mt * 16 + lg * 4 + j;
            u64 mb = mrow[q];
            const float* brow = biasb + (size_t)(head * 256 + q) * 64;
            float v[4];
            float m = -3.0e38f;
#pragma unroll
            for (int nt = 0; nt < 4; ++nt) {
                int key = nt * 16 + lr;
                float sv = s[mt][nt][j] + brow[key];
                if ((mb >> key) & 1ull) sv = -1.0e9f;
                v[nt] = sv;
                m = fmaxf(m, sv);
            }
#pragma unroll
            for (int d = 1; d < 16; d <<= 1) m = fmaxf(m, __shfl_xor(m, d, 64));
            float sum = 0.f;
#pragma unroll
            for (int nt = 0; nt < 4; ++nt) { v[nt] = __expf(v[nt] - m); sum += v[nt]; }
#pragma unroll
            for (int d = 1; d < 16; d <<= 1) sum += __shfl_xor(sum, d, 64);
            float inv = 1.0f / sum;
            int sw = (q & 7) << 4;
#pragma unroll
            for (int nt = 0; nt < 4; ++nt) {
                int off = q * 128 + (((nt * 16 + lr) * 2) ^ sw);
                *reinterpret_cast<unsigned short*>(Pb + off) = f2bf(v[nt] * inv);
            }
        }
    }

    __syncthreads();

    f32x4 o[4][2];
#pragma unroll
    for (int mt = 0; mt < 4; ++mt)
#pragma unroll
        for (int nt = 0; nt < 2; ++nt) o[mt][nt] = {0.f, 0.f, 0.f, 0.f};
#pragma unroll
    for (int kc = 0; kc < 2; ++kc) {
        short8v pf[4], vf[2];
#pragma unroll
        for (int mt = 0; mt < 4; ++mt) {
            int row = qb + mt * 16 + lr;
            int coff = (kc * 64 + lg * 16) ^ ((row & 7) << 4);
            pf[mt] = *reinterpret_cast<const short8v*>(Pb + row * 128 + coff);
        }
#pragma unroll
        for (int nt = 0; nt < 2; ++nt)
            vf[nt] = *reinterpret_cast<const short8v*>(&Vt[nt * 16 + lr][kc * 32 + lg * 8]);
        __builtin_amdgcn_s_setprio(1);
#pragma unroll
        for (int mt = 0; mt < 4; ++mt)
#pragma unroll
            for (int nt = 0; nt < 2; ++nt)
                o[mt][nt] = __builtin_amdgcn_mfma_f32_16x16x32_bf16(pf[mt], vf[nt], o[mt][nt], 0, 0, 0);
        __builtin_amdgcn_s_setprio(0);
    }

#pragma unroll
    for (int mt = 0; mt < 4; ++mt)
#pragma unroll
        for (int j = 0; j < 4; ++j) {
            int q = qb + mt * 16 + lg * 4 + j;
            int gr = (wi * 16 + (q >> 4) + 8) & 127;
            int gc = (wj * 16 + (q & 15) + 8) & 127;
            unsigned short* dst =
                Qbuf + ((size_t)(b * 16384 + gr * 128 + gc)) * 256 + head * 32;
#pragma unroll
            for (int nt = 0; nt < 2; ++nt)
                dst[nt * 16 + lr] = f2bf(o[mt][nt][j]);
        }
}

// ---------------------------------------------------------------------------
extern "C" void kernel_launch(void* const* d_in, const int* in_sizes, int n_in,
                              void* d_out, int out_size, void* d_ws, size_t ws_size,
                              hipStream_t stream) {
    const float* x    = (const float*)d_in[0];
    const float* z    = (const float*)d_in[1];
    const int*   mask = (const int*)d_in[2];
    const float* Wq   = (const float*)d_in[3];
    const float* bq   = (const float*)d_in[4];
    const float* Wkv  = (const float*)d_in[5];
    const float* bkv  = (const float*)d_in[6];
    const float* Wo   = (const float*)d_in[7];
    const float* bo   = (const float*)d_in[8];
    const float* rel  = (const float*)d_in[9];
    float* out = (float*)d_out;

    // workspace layout (~103 MB)
    char* ws = (char*)d_ws;
    unsigned short* Qbuf  = (unsigned short*)(ws);                 // 67,108,864 B
    unsigned short* KVbuf = (unsigned short*)(ws + 67108864);      // 33,554,432 B
    unsigned short* WqT   = (unsigned short*)(ws + 100663296);     //    131,072 B
    unsigned short* WkvT  = (unsigned short*)(ws + 100794368);     //    262,144 B
    unsigned short* WoT   = (unsigned short*)(ws + 101056512);     //    131,072 B
    float*          biasb = (float*)(ws + 101187584);              //    524,288 B
    u64*            maskp = (u64*)(ws + 101711872);                //  1,048,576 B
    float*          bqs   = (float*)(ws + 102760448);              //      1,024 B

    prep_weights<<<1024, 256, 0, stream>>>(Wq, Wkv, Wo, WqT, WkvT, WoT);
    prep_bias<<<513, 256, 0, stream>>>(rel, bq, biasb, bqs);
    prep_mask<<<512, 256, 0, stream>>>(mask, maskp);

    // Q = x @ (Wq*scale) + bq*scale -> bf16 [131072, 256]  (2-phase counted)
    gemm_q2<<<512, 512, 0, stream>>>(x, WqT, bqs, Qbuf);
    // KV = z @ Wkv + bkv -> bf16 [32768, 512]
    gemm_proj<true, true><<<dim3(4, 256), 256, 0, stream>>>(
        (const void*)z, WkvT, bkv, (void*)KVbuf, 32768, 512, 256);
    // fused window attention (in-place into Qbuf)
    win_attn<<<dim3(64, 8, 8), 256, 0, stream>>>(Qbuf, KVbuf, maskp, biasb);
    // out = attn @ Wo + bo -> f32  (2-phase counted)
    gemm_o2<<<512, 512, 0, stream>>>(Qbuf, WoT, bo, out);
}